// Round 15
// baseline (171.651 us; speedup 1.0000x reference)
//
#include <hip/hip_runtime.h>
#include <hip/hip_bf16.h>
#include <math.h>

// Problem constants
#define B_  8
#define T_  2048
#define C_  768
#define HS_ 256

// Split-K flash: q-block = 64 rows, k-tile = 32 keys, chunk = 16 k-tiles
// (512 keys). q-block qb (0..31) has 2qb+2 k-tiles; chunks(qb) = (qb>>3)+1;
// per-batch chunk total = 80; blocks = 8 * 80 = 640.
#define CHUNKS_PER_BATCH 80
#define NSLOT (CHUNKS_PER_BATCH * B_)   // 640

typedef float  f32x4  __attribute__((ext_vector_type(4)));
typedef __bf16 bf16x8 __attribute__((ext_vector_type(8)));
typedef __bf16 bf16x4 __attribute__((ext_vector_type(4)));
typedef __bf16 bf16x2 __attribute__((ext_vector_type(2)));

#define MFMA16(a, b, c) __builtin_amdgcn_mfma_f32_16x16x32_bf16((a), (b), (c), 0, 0, 0)

// global->LDS async copy, 16B per lane (dest = wave-uniform base + lane*16)
#define GLOAD_LDS16(gp, lp)                                                     \
    __builtin_amdgcn_global_load_lds(                                           \
        (const __attribute__((address_space(1))) void*)(gp),                    \
        (__attribute__((address_space(3))) void*)(lp), 16, 0, 0)

// cumulative chunk count before q-block qb: g=qb>>3 -> 4g(g+1) + (qb&7)(g+1)
__device__ __forceinline__ int chunk_cum64(int qb) {
    int g = qb >> 3;
    return 4 * g * (g + 1) + (qb & 7) * (g + 1);
}

// ---------------------------------------------------------------------------
// Kernel 0: prep = x cast (blocks 0..6143) + weight transpose (6144..6431).
// ---------------------------------------------------------------------------
__global__ __launch_bounds__(256) void prep_kernel(const float* __restrict__ x,
                                                   const float* __restrict__ Wq,
                                                   const float* __restrict__ Wk,
                                                   const float* __restrict__ Wv,
                                                   __bf16* __restrict__ xb,
                                                   __bf16* __restrict__ wt_all,
                                                   float qscale) {
    const int bid = blockIdx.x;
    if (bid < 6144) {
        size_t i = ((size_t)bid * 256 + threadIdx.x) * 8;
        f32x4 a = *(const f32x4*)(x + i);
        f32x4 b = *(const f32x4*)(x + i + 4);
        bf16x8 o;
        o[0] = (__bf16)a[0]; o[1] = (__bf16)a[1]; o[2] = (__bf16)a[2]; o[3] = (__bf16)a[3];
        o[4] = (__bf16)b[0]; o[5] = (__bf16)b[1]; o[6] = (__bf16)b[2]; o[7] = (__bf16)b[3];
        *(bf16x8*)(xb + i) = o;
    } else {
        int idx = (bid - 6144) * 256 + threadIdx.x;   // [0, 73728)
        int n   = idx & 255;
        int t   = idx >> 8;          // [0, 288) = mat*96 + k8
        int mat = t / 96;
        int k8  = t - mat * 96;
        const float* W = (mat == 0) ? Wq : ((mat == 1) ? Wk : Wv);
        float scale = (mat == 0) ? qscale : 1.0f;
        bf16x8 o;
#pragma unroll
        for (int j = 0; j < 8; j++)
            o[j] = (__bf16)(W[(k8 * 8 + j) * HS_ + n] * scale);
        *(bf16x8*)&wt_all[((size_t)mat * HS_ + n) * C_ + k8 * 8] = o;
    }
}

// ---------------------------------------------------------------------------
// Kernel 2: fused QKV GEMM. BK=32, double-buffered LDS, one barrier/iter.
//   + R19 bank-conflict swizzle (pre-swizzled global source, linear LDS
//   dest, matching slot on fragment reads).
// Fragment layouts (element index, all *8 = 8 bf16 per lane slot):
//   Q: ((((b*32+qt)*4 + w16)*8 + ks )*64 + lane)   lane&15 = q, quad = (d>>3)&3, j = d&7
//   K: ((((b*32+kt)*8 + ks )*4 + ns )*64 + lane)   lane&15 = s, quad = (d>>3)&3, j = d&7
//   V: ((((b*32+kt)*2 + ks2)*16 + ntv)*64 + lane)  lane&15 = d, quad = (s>>3)&3, j = s&7
// ---------------------------------------------------------------------------
__global__ __launch_bounds__(256) void proj_kernel(const __bf16* __restrict__ xb,
                                                   const __bf16* __restrict__ wt,
                                                   __bf16* __restrict__ qf_,
                                                   __bf16* __restrict__ kf_,
                                                   __bf16* __restrict__ vf_) {
    __shared__ alignas(16) __bf16 ldsA[2][128 * 32];   // 2 x 8 KB
    __shared__ alignas(16) __bf16 ldsB[2][128 * 32];   // 2 x 8 KB

    const int tid  = threadIdx.x;
    const int w    = tid >> 6;
    const int lane = tid & 63;
    const int cm   = lane & 15;
    const int quad = lane >> 4;
    const int wm   = w & 1;
    const int wn   = w >> 1;
    const int m0   = blockIdx.x * 128;
    const int n0   = blockIdx.y * 128;
    const int mat  = n0 >> 8;                 // 0=Q 1=K 2=V

    // swizzled 16B-slot for fragment reads: row R has global granule `quad`
    // stored at slot quad ^ ((R>>1)&3); R = (16-mult) + cm -> (R>>1)&3 = (cm>>1)&3
    const int sw = (quad ^ ((cm >> 1) & 3)) * 8;

    f32x4 acc[4][4];
#pragma unroll
    for (int i = 0; i < 4; i++)
#pragma unroll
        for (int j = 0; j < 4; j++) acc[i][j] = (f32x4){0.f, 0.f, 0.f, 0.f};

    // prologue: stage k-iter 0 into buffer 0 (global granule pre-swizzled)
#pragma unroll
    for (int h = 0; h < 2; h++) {
        int c  = tid + h * 256;   // 512 chunks: row = c>>2, LDS slot = c&3
        int gg = (c & 3) ^ ((c >> 3) & 3);   // global granule for this slot
        GLOAD_LDS16(xb + (size_t)(m0 + (c >> 2)) * C_ + gg * 8, &ldsA[0][c * 8]);
        GLOAD_LDS16(wt + (size_t)(n0 + (c >> 2)) * C_ + gg * 8, &ldsB[0][c * 8]);
    }

    for (int kt = 0; kt < 24; kt++) {
        const int cur = kt & 1;
        __syncthreads();   // drains vmcnt -> buf[cur] staged; prev reads done

        if (kt < 23) {
            const int k0 = (kt + 1) * 32;
#pragma unroll
            for (int h = 0; h < 2; h++) {
                int c  = tid + h * 256;
                int gg = (c & 3) ^ ((c >> 3) & 3);
                GLOAD_LDS16(xb + (size_t)(m0 + (c >> 2)) * C_ + k0 + gg * 8,
                            &ldsA[cur ^ 1][c * 8]);
                GLOAD_LDS16(wt + (size_t)(n0 + (c >> 2)) * C_ + k0 + gg * 8,
                            &ldsB[cur ^ 1][c * 8]);
            }
        }

        bf16x8 af[4], bfr[4];
#pragma unroll
        for (int mt = 0; mt < 4; mt++)
            af[mt] = *(const bf16x8*)&ldsA[cur][(wm * 64 + mt * 16 + cm) * 32 + sw];
#pragma unroll
        for (int nt = 0; nt < 4; nt++)
            bfr[nt] = *(const bf16x8*)&ldsB[cur][(wn * 64 + nt * 16 + cm) * 32 + sw];
        if (mat < 2) {
#pragma unroll
            for (int dt = 0; dt < 4; dt++)
#pragma unroll
                for (int qt2 = 0; qt2 < 4; qt2++)
                    acc[dt][qt2] = MFMA16(bfr[dt], af[qt2], acc[dt][qt2]);
        } else {
#pragma unroll
            for (int mt = 0; mt < 4; mt++)
#pragma unroll
                for (int nt = 0; nt < 4; nt++)
                    acc[mt][nt] = MFMA16(af[mt], bfr[nt], acc[mt][nt]);
        }
    }

    const int dBase = (n0 & 255) + wn * 64;
    const int b     = m0 >> 11;
    if (mat < 2) {
        const int rt2 = ((m0 & 2047) >> 6) + wm;   // 64-row tile within batch
        __bf16* dst = (mat == 0) ? qf_ : kf_;
#pragma unroll
        for (int dt = 0; dt < 4; dt++)
#pragma unroll
            for (int qt2 = 0; qt2 < 4; qt2++) {
                int d0    = dBase + dt * 16 + quad * 4;   // d of reg i = d0 + i
                int ksq   = d0 >> 5;
                int quadp = (d0 >> 3) & 3;
                int j0    = d0 & 7;
                size_t addr;
                if (mat == 0)
                    addr = ((((size_t)(b * 32 + rt2) * 4 + qt2) * 8 + ksq) * 64
                            + quadp * 16 + cm) * 8 + j0;
                else
                    addr = ((((size_t)(b * 32 + rt2) * 8 + ksq) * 4 + qt2) * 64
                            + quadp * 16 + cm) * 8 + j0;
                bf16x4 v4;
                v4[0] = (__bf16)acc[dt][qt2][0]; v4[1] = (__bf16)acc[dt][qt2][1];
                v4[2] = (__bf16)acc[dt][qt2][2]; v4[3] = (__bf16)acc[dt][qt2][3];
                *(bf16x4*)(dst + addr) = v4;
            }
    } else {
        const int rt = ((m0 & 2047) + wm * 64) >> 6;
#pragma unroll
        for (int mt = 0; mt < 4; mt++) {
            int ks2   = (mt >> 1) & 1;
            int quadF = (mt & 1) * 2 + (quad >> 1);
            int jb    = (quad & 1) * 4;
#pragma unroll
            for (int nt = 0; nt < 4; nt++) {
                int ntv = (dBase >> 4) + nt;
                size_t idx = ((((size_t)(b * 32 + rt) * 2 + ks2) * 16 + ntv) * 64
                              + quadF * 16 + cm) * 8 + jb;
                bf16x4 v4;
                v4[0] = (__bf16)acc[mt][nt][0]; v4[1] = (__bf16)acc[mt][nt][1];
                v4[2] = (__bf16)acc[mt][nt][2]; v4[3] = (__bf16)acc[mt][nt][3];
                *(bf16x4*)(vf_ + idx) = v4;
            }
        }
    }
}

// ---------------------------------------------------------------------------
// Kernel 3a: split-K causal flash partial — R22: R21 + K-PREFETCH UNDER PV.
//   R21 exposed K's own L2 latency (K issued, then vmcnt(4) waits with only
//   V-issue in between). Rotation: at barrier C every wave's K ds_reads are
//   done (QK precedes P-write) -> ldsK reusable -> issue K(t+1) right after
//   C; it flies under PV + loop-top barrier A + V(t+1)-issue. V(t) issued
//   after A hides under QK+softmax as in R21. Counting exact: at vmcnt(4)
//   the 4 oldest ops are K(t) -> K tile landed; vmcnt(0) at C drains V(t)
//   (K(t+1) issued after C's wait). Same LDS/occupancy/math as R21.
// ---------------------------------------------------------------------------
__global__ __launch_bounds__(256, 3) void flash_part(const __bf16* __restrict__ qf_,
                                                     const __bf16* __restrict__ kf_,
                                                     const __bf16* __restrict__ vf_,
                                                     __bf16* __restrict__ Opart,
                                                     float* __restrict__ mpart,
                                                     float* __restrict__ lpart) {
    __shared__ alignas(16) __bf16 ldsK[8 * 2 * 64 * 8];   // [ks8][ns2][lane]x8 = 16 KB
    __shared__ alignas(16) __bf16 ldsV[16 * 64 * 8];      // [ntv16][lane]x8  = 16 KB
    __shared__ alignas(16) __bf16 ldsP[4][512];           // per-q-tile P (shared, 4 KB)

    const int tid  = threadIdx.x;
    const int w    = tid >> 6;       // 0..3
    const int lane = tid & 63;
    const int cm   = lane & 15;      // = q column
    const int quad = lane >> 4;

    const int pid  = blockIdx.x;                // [0, 640)
    const int b    = pid & 7;                   // batch -> XCD spread
    const int r    = (CHUNKS_PER_BATCH - 1) - (pid >> 3);   // heavy chunks first
    int qb = 0, ci = 0;
    {
        int rr = r;
        for (int j = 0; j < 32; j++) {
            int c = (j >> 3) + 1;
            if (rr < c) { qb = j; ci = rr; break; }
            rr -= c;
        }
    }
    const int lpid = b * CHUNKS_PER_BATCH + r;  // output slot
    const int kt_begin = ci * 16;                       // 32-key tiles
    const int kt_end   = min(kt_begin + 16, 2 * qb + 2);

    // Q fragments (B-operand: lane&15 = q, quad*8+j = d), coalesced loads.
    const __bf16* qp = qf_ + (((size_t)(b * 32 + qb) * 4 + w) * 8) * 512 + lane * 8;
    bf16x8 qf[8];
#pragma unroll
    for (int ks = 0; ks < 8; ks++) qf[ks] = *(const bf16x8*)(qp + ks * 512);

    // accO[nt4][qt][i]: d = (w*4+nt4)*16 + quad*4 + i, q = qt*16 + cm
    f32x4 accO[4][4];
#pragma unroll
    for (int nt4 = 0; nt4 < 4; nt4++)
#pragma unroll
        for (int qt = 0; qt < 4; qt++) accO[nt4][qt] = (f32x4){0.f, 0.f, 0.f, 0.f};
    float mi = 0.f, li = 0.f;        // mi fixed after first tile (wave's q-tile = w)

    const int wrow  = qb * 64 + w * 16;
    const int qglob = wrow + cm;

    // per-wave staging helpers: 4 x GLOAD each
    auto stageK = [&](int kt) {
        const int kt64 = kt >> 1, kh = kt & 1;
        const __bf16* kgb = kf_ + (((size_t)(b * 32 + kt64) * 8) * 4 + kh * 2) * 512;
#pragma unroll
        for (int h = 0; h < 4; h++) {
            int g = h * 256 + tid;           // 16B slot id, 0..1023
            int ks = g >> 7, sub = g & 127;  // sub = ns2*64 + lane'
            GLOAD_LDS16(kgb + (size_t)ks * 4 * 512 + sub * 8,
                        ldsK + (h * 256 + w * 64) * 8);
        }
    };
    auto stageV = [&](int kt) {
        const __bf16* vgb = vf_ + ((size_t)(b * 64 + kt) * 16) * 512;
#pragma unroll
        for (int h = 0; h < 4; h++) {
            int g = h * 256 + tid;           // ntv = g>>6, lane' = g&63
            GLOAD_LDS16(vgb + (size_t)g * 8,
                        ldsV + (h * 256 + w * 64) * 8);
        }
    };

    // prologue: K(first) in flight before the loop
    stageK(kt_begin);

    for (int kt = kt_begin; kt < kt_end; kt++) {
        __syncthreads();   // (A) prior tile's V reads + P consumed -> ldsV free
        stageV(kt);        // V(kt) flies under QK + softmax

        // (B) K(kt) drain: 4 oldest VMEM ops are K(kt); block barrier ->
        //     whole K tile visible. V(kt) stays in flight.
        asm volatile("s_waitcnt vmcnt(4)" ::: "memory");
        __builtin_amdgcn_s_barrier();

        // ---- St = K Q^T  (32 s x 16 q per wave; wave's own q-tile w) ----
        f32x4 s[2];
#pragma unroll
        for (int i = 0; i < 2; i++) s[i] = (f32x4){0.f, 0.f, 0.f, 0.f};
#pragma unroll
        for (int ns = 0; ns < 2; ns++)
#pragma unroll
            for (int ks = 0; ks < 8; ks++) {
                bf16x8 kfr = *(const bf16x8*)&ldsK[(ks * 2 + ns) * 512 + lane * 8];
                s[ns] = MFMA16(kfr, qf[ks], s[ns]);
            }
        // ---- causal mask ----
        if (kt * 32 + 31 > wrow) {
#pragma unroll
            for (int ns = 0; ns < 2; ns++)
#pragma unroll
                for (int i = 0; i < 4; i++)
                    if (kt * 32 + ns * 16 + quad * 4 + i > qglob)
                        s[ns][i] = -__builtin_inff();
        }
        // ---- fixed-anchor softmax: establish m once (first tile) ----
        if (kt == kt_begin) {
            float pm = -__builtin_inff();
#pragma unroll
            for (int ns = 0; ns < 2; ns++)
#pragma unroll
                for (int i = 0; i < 4; i++) pm = fmaxf(pm, s[ns][i]);
            pm = fmaxf(pm, __shfl_xor(pm, 16));
            pm = fmaxf(pm, __shfl_xor(pm, 32));
            mi = pm;
        }
        float p[2][4], rs = 0.f;
#pragma unroll
        for (int ns = 0; ns < 2; ns++)
#pragma unroll
            for (int i = 0; i < 4; i++) {
                p[ns][i] = exp2f(s[ns][i] - mi);
                rs += p[ns][i];
            }
        rs += __shfl_xor(rs, 16);
        rs += __shfl_xor(rs, 32);
        li += rs;

        // ---- P (wave's q-tile w) -> shared LDS in PV B-operand layout ----
#pragma unroll
        for (int ns = 0; ns < 2; ns++)
#pragma unroll
            for (int i2 = 0; i2 < 2; i2++) {
                bf16x2 d2;
                d2[0] = (__bf16)p[ns][2 * i2];
                d2[1] = (__bf16)p[ns][2 * i2 + 1];
                int off = ((ns * 2 + (quad >> 1)) * 16 + cm) * 8
                          + (quad & 1) * 4 + i2 * 2;
                *(bf16x2*)&ldsP[w][off] = d2;
            }
        // (C) V(kt) drain + P visibility; all waves' K reads done -> ldsK free
        asm volatile("s_waitcnt vmcnt(0)" ::: "memory");
        __builtin_amdgcn_s_barrier();

        // prefetch next tile's K under PV
        if (kt + 1 < kt_end) stageK(kt + 1);

        // ---- O += V^T-frag x P-frag; wave w owns d-slice [64w, 64w+64) ----
        bf16x8 pf[4];
#pragma unroll
        for (int qt = 0; qt < 4; qt++)
            pf[qt] = *(const bf16x8*)&ldsP[qt][(quad * 16 + cm) * 8];
#pragma unroll
        for (int nt4 = 0; nt4 < 4; nt4++) {
            bf16x8 vfr = *(const bf16x8*)&ldsV[((w * 4 + nt4) * 64 + lane) * 8];
#pragma unroll
            for (int qt = 0; qt < 4; qt++)
                accO[nt4][qt] = MFMA16(vfr, pf[qt], accO[nt4][qt]);
        }
    }

    // ---- epilogue: coalesced bf16x4 stores + fp32 (m, l) ----
#pragma unroll
    for (int qt = 0; qt < 4; qt++) {
        __bf16* op = Opart + ((size_t)lpid * 64 + qt * 16 + cm) * HS_;
#pragma unroll
        for (int nt4 = 0; nt4 < 4; nt4++) {
            bf16x4 v4;
            v4[0] = (__bf16)accO[nt4][qt][0]; v4[1] = (__bf16)accO[nt4][qt][1];
            v4[2] = (__bf16)accO[nt4][qt][2]; v4[3] = (__bf16)accO[nt4][qt][3];
            *(bf16x4*)(op + (w * 4 + nt4) * 16 + quad * 4) = v4;
        }
    }
    if (quad == 0) {
        mpart[lpid * 64 + w * 16 + cm] = mi;
        lpart[lpid * 64 + w * 16 + cm] = li;
    }
}

// ---------------------------------------------------------------------------
// Kernel 3b: combine partials.  Grid (256, 4): block = (b, qb) x 16 rows.
// ---------------------------------------------------------------------------
__global__ __launch_bounds__(256) void flash_combine(const __bf16* __restrict__ Opart,
                                                     const float* __restrict__ mpart,
                                                     const float* __restrict__ lpart,
                                                     float* __restrict__ out) {
    const int b    = blockIdx.x >> 5;
    const int qb   = blockIdx.x & 31;
    const int nc   = (qb >> 3) + 1;
    const int pid0 = b * CHUNKS_PER_BATCH + chunk_cum64(qb);

    const int tid  = threadIdx.x;
    const int col  = (tid & 63) * 4;
    const int r0   = blockIdx.y * 16 + (tid >> 6) * 4;

    f32x4 ms = (f32x4){-__builtin_inff(), -__builtin_inff(),
                       -__builtin_inff(), -__builtin_inff()};
    for (int c = 0; c < nc; c++) {
        f32x4 m4 = *(const f32x4*)(mpart + (pid0 + c) * 64 + r0);
#pragma unroll
        for (int i = 0; i < 4; i++) ms[i] = fmaxf(ms[i], m4[i]);
    }
    f32x4 acc[4];
#pragma unroll
    for (int i = 0; i < 4; i++) acc[i] = (f32x4){0.f, 0.f, 0.f, 0.f};
    f32x4 lt = (f32x4){0.f, 0.f, 0.f, 0.f};
    for (int c = 0; c < nc; c++) {
        f32x4 m4 = *(const f32x4*)(mpart + (pid0 + c) * 64 + r0);
        f32x4 l4 = *(const f32x4*)(lpart + (pid0 + c) * 64 + r0);
#pragma unroll
        for (int i = 0; i < 4; i++) {
            float sc = exp2f(m4[i] - ms[i]);
            lt[i] += l4[i] * sc;
            bf16x4 o = *(const bf16x4*)(Opart
                        + ((size_t)(pid0 + c) * 64 + r0 + i) * HS_ + col);
            acc[i][0] += (float)o[0] * sc; acc[i][1] += (float)o[1] * sc;
            acc[i][2] += (float)o[2] * sc; acc[i][3] += (float)o[3] * sc;
        }
    }
#pragma unroll
    for (int i = 0; i < 4; i++) {
        float inv = 1.0f / lt[i];
        f32x4 res = (f32x4){acc[i][0] * inv, acc[i][1] * inv,
                            acc[i][2] * inv, acc[i][3] * inv};
        *(f32x4*)(out + ((size_t)(b * T_ + qb * 64 + r0 + i)) * HS_ + col) = res;
    }
}

// ---------------------------------------------------------------------------
extern "C" void kernel_launch(void* const* d_in, const int* in_sizes, int n_in,
                              void* d_out, int out_size, void* d_ws, size_t ws_size,
                              hipStream_t stream) {
    const float* x  = (const float*)d_in[0];
    const float* Wq = (const float*)d_in[1];
    const float* Wk = (const float*)d_in[2];
    const float* Wv = (const float*)d_in[3];
    float* out = (float*)d_out;

    char* ws = (char*)d_ws;
    size_t off = 0;
    __bf16* wt_all = (__bf16*)(ws + off); off += 1179648;
    __bf16* qfrag  = (__bf16*)(ws + off); off += 8388608;
    __bf16* kfrag  = (__bf16*)(ws + off); off += 8388608;
    __bf16* vfrag  = (__bf16*)(ws + off); off += 8388608;
    __bf16* xb     = (__bf16*)(ws + off);              // union with Opart
    __bf16* Opart  = (__bf16*)(ws + off); off += (size_t)NSLOT * 64 * HS_ * 2;
    float*  mpart  = (float*)(ws + off);  off += (size_t)NSLOT * 64 * 4;
    float*  lpart  = (float*)(ws + off);

    float qscale = 1.4426950408889634f / sqrtf((float)C_);

    prep_kernel<<<dim3(6432), 256, 0, stream>>>(x, Wq, Wk, Wv, xb, wt_all, qscale);
    proj_kernel<<<dim3(128, 6), 256, 0, stream>>>(xb, wt_all, qfrag, kfrag, vfrag);
    flash_part<<<dim3(NSLOT), 256, 0, stream>>>(qfrag, kfrag, vfrag, Opart, mpart, lpart);
    flash_combine<<<dim3(256, 4), 256, 0, stream>>>(Opart, mpart, lpart, out);
}